// Round 1
// baseline (486.400 us; speedup 1.0000x reference)
//
#include <hip/hip_runtime.h>
#include <math.h>

#define HH 56
#define WW 56
#define CC 256
#define TT 8
#define HW 3136

// ---------------- K1: attn = sigmoid(relu(conv2d(x,w)+b)) ----------------
// block = (bt, 4-row h-tile); loop channels in chunks of 4, staged in LDS.
constexpr int K1_TILE_H = 4;
constexpr int K1_ROWS = K1_TILE_H + 2;   // 6
constexpr int K1_COLS = WW + 2;          // 58
constexpr int K1_CCH  = 4;

__global__ __launch_bounds__(256)
void k1_attn(const float* __restrict__ x, const float* __restrict__ aw,
             const float* __restrict__ ab, float* __restrict__ attn) {
    const int blk = blockIdx.x;
    const int bt  = blk / 14;
    const int h0  = (blk % 14) * K1_TILE_H;
    __shared__ float tile[K1_CCH][K1_ROWS][K1_COLS];
    const int tid = threadIdx.x;
    const int wc  = tid % WW;
    const int hr  = tid / WW;
    const bool active = tid < K1_TILE_H * WW;
    float acc[4] = {0.f, 0.f, 0.f, 0.f};
    const float* xb = x + (size_t)bt * CC * HW;

    for (int c0 = 0; c0 < CC; c0 += K1_CCH) {
        __syncthreads();
        for (int idx = tid; idx < K1_CCH * K1_ROWS * K1_COLS; idx += 256) {
            int cl  = idx / (K1_ROWS * K1_COLS);
            int rem = idx - cl * (K1_ROWS * K1_COLS);
            int r   = rem / K1_COLS;
            int col = rem - r * K1_COLS;
            int gh = h0 + r - 1, gw = col - 1;
            float v = 0.f;
            if (gh >= 0 && gh < HH && (unsigned)gw < WW)
                v = xb[(size_t)(c0 + cl) * HW + gh * WW + gw];
            tile[cl][r][col] = v;
        }
        __syncthreads();
        if (active) {
            #pragma unroll
            for (int cl = 0; cl < K1_CCH; ++cl) {
                float v[9];
                #pragma unroll
                for (int ki = 0; ki < 3; ++ki)
                    #pragma unroll
                    for (int kj = 0; kj < 3; ++kj)
                        v[ki * 3 + kj] = tile[cl][hr + ki][wc + kj];
                const int c = c0 + cl;
                #pragma unroll
                for (int o = 0; o < 4; ++o) {
                    const float* wp = aw + ((size_t)o * CC + c) * 9;
                    float s = 0.f;
                    #pragma unroll
                    for (int k = 0; k < 9; ++k) s = fmaf(wp[k], v[k], s);
                    acc[o] += s;
                }
            }
        }
    }
    if (active) {
        #pragma unroll
        for (int o = 0; o < 4; ++o) {
            float z = acc[o] + ab[o];
            z = fmaxf(z, 0.f);                       // relu
            float s = 1.f / (1.f + expf(-z));        // sigmoid
            attn[((size_t)bt * 4 + o) * HW + (h0 + hr) * WW + wc] = s;
        }
    }
}

// ---------------- K2: per-channel BN partial sums of xh = x*attn ----------
__global__ __launch_bounds__(256)
void k2_stats(const float* __restrict__ x, const float* __restrict__ attn,
              float* __restrict__ bn_sum, float* __restrict__ bn_sumsq) {
    const int c  = blockIdx.x & 255;
    const int bt = blockIdx.x >> 8;
    const int head = c >> 6;
    const float4* xp = (const float4*)(x + ((size_t)bt * CC + c) * HW);
    const float4* ap = (const float4*)(attn + ((size_t)bt * 4 + head) * HW);
    float s = 0.f, s2 = 0.f;
    for (int i = threadIdx.x; i < HW / 4; i += 256) {
        float4 xv = xp[i], av = ap[i];
        float v0 = xv.x * av.x, v1 = xv.y * av.y, v2 = xv.z * av.z, v3 = xv.w * av.w;
        s  += v0 + v1 + v2 + v3;
        s2 += v0 * v0 + v1 * v1 + v2 * v2 + v3 * v3;
    }
    #pragma unroll
    for (int off = 32; off > 0; off >>= 1) {
        s  += __shfl_down(s, off);
        s2 += __shfl_down(s2, off);
    }
    __shared__ float red[8];
    const int wave = threadIdx.x >> 6;
    if ((threadIdx.x & 63) == 0) { red[wave * 2] = s; red[wave * 2 + 1] = s2; }
    __syncthreads();
    if (threadIdx.x == 0) {
        atomicAdd(&bn_sum[c],   red[0] + red[2] + red[4] + red[6]);
        atomicAdd(&bn_sumsq[c], red[1] + red[3] + red[5] + red[7]);
    }
}

// ---------------- K3: finalize BN -> per-channel scale/shift --------------
__global__ void k3_final(const float* __restrict__ bn_sum, const float* __restrict__ bn_sumsq,
                         const float* __restrict__ gamma, const float* __restrict__ beta,
                         float* __restrict__ scale, float* __restrict__ shift) {
    int c = threadIdx.x;
    const float invN = 1.f / 100352.f;            // B*T*H*W
    float mean = bn_sum[c] * invN;
    float var  = bn_sumsq[c] * invN - mean * mean;
    float sc   = gamma[c] * rsqrtf(var + 1e-5f);
    scale[c] = sc;
    shift[c] = fmaf(-mean, sc, beta[c]);
}

// ---------------- K4: grouped dilated conv3d partial sums -----------------
// block = (b, 4-row h-tile, 16-channel chunk). xr computed at staging time.
// Accumulators acc[dil][t_out], fully static indexing; atomicAdd to gate_raw.
__global__ __launch_bounds__(256)
void k4_gate(const float* __restrict__ x, const float* __restrict__ attn,
             const float* __restrict__ scale, const float* __restrict__ shift,
             const float* __restrict__ gw0, const float* __restrict__ gw1,
             float* __restrict__ gate_raw) {
    const int blk   = blockIdx.x;
    const int chunk = blk & 15;
    const int ht    = (blk >> 4) % 14;
    const int b     = blk / (16 * 14);
    const int h0    = ht * 4;
    const int g     = chunk >> 3;           // channels 0..127 -> g0, 128..255 -> g1
    __shared__ float tile[TT][6][58];       // 11136 B
    const int tid = threadIdx.x;
    const int wc  = tid % WW;
    const int hr  = tid / WW;
    const bool active = tid < 4 * WW;
    float acc[2][8];
    #pragma unroll
    for (int d = 0; d < 2; ++d)
        #pragma unroll
        for (int t = 0; t < 8; ++t) acc[d][t] = 0.f;

    for (int cl = 0; cl < 16; ++cl) {
        const int c = chunk * 16 + cl;
        const float sc = scale[c], sh = shift[c];
        const int head = c >> 6;
        __syncthreads();
        // stage xr = relu(x*attn*sc + sh) for all 8 t planes, with spatial halo
        for (int idx = tid; idx < TT * 6 * 58; idx += 256) {
            int t   = idx / 348;
            int rem = idx - t * 348;
            int r   = rem / 58;
            int col = rem - r * 58;
            int gh = h0 + r - 1, gw = col - 1;
            float v = 0.f;
            if (gh >= 0 && gh < HH && (unsigned)gw < WW) {
                int bti = b * TT + t;
                float xv = x[((size_t)bti * CC + c) * HW + gh * WW + gw];
                float av = attn[((size_t)bti * 4 + head) * HW + gh * WW + gw];
                v = fmaxf(fmaf(xv * av, sc, sh), 0.f);
            }
            tile[t][r][col] = v;
        }
        __syncthreads();
        if (active) {
            const int ci = c & 127;
            const float* wp0 = gw0 + ((size_t)g * 128 + ci) * 27;  // dil 1 weights
            const float* wp1 = gw1 + ((size_t)g * 128 + ci) * 27;  // dil 2 weights
            #pragma unroll
            for (int t = 0; t < 8; ++t) {     // t_in
                float v[9];
                #pragma unroll
                for (int ki = 0; ki < 3; ++ki)
                    #pragma unroll
                    for (int kj = 0; kj < 3; ++kj)
                        v[ki * 3 + kj] = tile[t][hr + ki][wc + kj];
                #pragma unroll
                for (int kd = 0; kd < 3; ++kd) {
                    {   // dilation 1: t_out = t_in + (1-kd)*1
                        const int to = t + (1 - kd);
                        if (to >= 0 && to < 8) {
                            float s = 0.f;
                            #pragma unroll
                            for (int k = 0; k < 9; ++k) s = fmaf(wp0[kd * 9 + k], v[k], s);
                            acc[0][to] += s;
                        }
                    }
                    {   // dilation 2: t_out = t_in + (1-kd)*2
                        const int to = t + 2 * (1 - kd);
                        if (to >= 0 && to < 8) {
                            float s = 0.f;
                            #pragma unroll
                            for (int k = 0; k < 9; ++k) s = fmaf(wp1[kd * 9 + k], v[k], s);
                            acc[1][to] += s;
                        }
                    }
                }
            }
        }
    }
    if (active) {
        #pragma unroll
        for (int d = 0; d < 2; ++d)
            #pragma unroll
            for (int t = 0; t < 8; ++t)
                atomicAdd(&gate_raw[(((size_t)(d * 4 + b) * 2 + g) * 8 + t) * HW
                                    + (h0 + hr) * WW + wc], acc[d][t]);
    }
}

// ---------------- K4b: gate = tanh(raw + bias) ----------------------------
__global__ void k4b_tanh(const float* __restrict__ raw, const float* __restrict__ gb0,
                         const float* __restrict__ gb1, float* __restrict__ gt) {
    int i = blockIdx.x * 256 + threadIdx.x;
    if (i >= 401408) return;
    int d   = i / 200704;
    int rem = i - d * 200704;
    int g   = (rem / 25088) & 1;        // 8*3136 per (g) slab
    float bias = (d == 0) ? gb0[g] : gb1[g];
    gt[i] = tanhf(raw[i] + bias);
}

// ---------------- K5: fuse + shuffle + alpha-combine ----------------------
// thread owns (b, c_out, hw) across all 8 t: x read exactly once.
__global__ __launch_bounds__(256)
void k5_fuse(const float* __restrict__ x, const float* __restrict__ attn,
             const float* __restrict__ scale, const float* __restrict__ shift,
             const float* __restrict__ gt, const float* __restrict__ alpha,
             float* __restrict__ out) {
    const int blk  = blockIdx.x;
    const int tile = blk % 13;
    const int c    = (blk / 13) & 255;
    const int b    = blk / (13 * 256);
    const int hw   = tile * 256 + threadIdx.x;
    if (hw >= HW) return;
    const int clo  = c & 127;
    const int cs   = (c & 128) | ((clo & 1) << 6) | (clo >> 1);  // inverse shuffle
    const int g    = c >> 7;
    const int head = cs >> 6;
    const float sc = scale[cs], sh = shift[cs];
    float xr[8], G0[8], G1[8];
    #pragma unroll
    for (int t = 0; t < 8; ++t) {
        const int bti = b * 8 + t;
        float xv = x[((size_t)bti * CC + cs) * HW + hw];
        float av = attn[((size_t)bti * 4 + head) * HW + hw];
        xr[t] = fmaxf(fmaf(xv * av, sc, sh), 0.f);
        G0[t] = gt[(((size_t)(0 * 4 + b) * 2 + g) * 8 + t) * HW + hw];
        G1[t] = gt[(((size_t)(1 * 4 + b) * 2 + g) * 8 + t) * HW + hw];
    }
    const float a0 = alpha[0], a1 = alpha[1];
    #pragma unroll
    for (int t = 0; t < 8; ++t) {
        float v0, v1;
        if (g == 0) {   // shift-left group: neighbor at t+d
            v0 = xr[t] * (1.f - G0[t]) + (t + 1 < 8 ? G0[t + 1] * xr[t + 1] : 0.f);
            v1 = xr[t] * (1.f - G1[t]) + (t + 2 < 8 ? G1[t + 2] * xr[t + 2] : 0.f);
        } else {        // shift-right group: neighbor at t-d
            v0 = xr[t] * (1.f - G0[t]) + (t - 1 >= 0 ? G0[t - 1] * xr[t - 1] : 0.f);
            v1 = xr[t] * (1.f - G1[t]) + (t - 2 >= 0 ? G1[t - 2] * xr[t - 2] : 0.f);
        }
        out[((size_t)(b * 8 + t) * CC + c) * HW + hw] = fmaf(a0, v0, a1 * v1);
    }
}

extern "C" void kernel_launch(void* const* d_in, const int* in_sizes, int n_in,
                              void* d_out, int out_size, void* d_ws, size_t ws_size,
                              hipStream_t stream) {
    const float* x     = (const float*)d_in[0];
    const float* aw    = (const float*)d_in[1];
    const float* ab    = (const float*)d_in[2];
    const float* gamma = (const float*)d_in[3];
    const float* beta  = (const float*)d_in[4];
    const float* gw0   = (const float*)d_in[5];
    const float* gb0   = (const float*)d_in[6];
    const float* gw1   = (const float*)d_in[7];
    const float* gb1   = (const float*)d_in[8];
    const float* alpha = (const float*)d_in[9];
    float* out = (float*)d_out;
    float* ws  = (float*)d_ws;

    // ws layout (floats): [gate_raw 401408 | bn_sum 256 | bn_sumsq 256 |
    //                      attn 401408 | gate_tanh 401408 | scale 256 | shift 256]
    float* gate_raw = ws;
    float* bn_sum   = ws + 401408;
    float* bn_sumsq = ws + 401664;
    float* attn     = ws + 401920;
    float* gate_t   = ws + 803328;
    float* scale    = ws + 1204736;
    float* shift    = ws + 1204992;

    // zero the atomic-accumulated regions (gate_raw + bn_sum + bn_sumsq, contiguous)
    hipMemsetAsync(gate_raw, 0, (size_t)(401408 + 512) * sizeof(float), stream);

    k1_attn <<<dim3(448),   dim3(256), 0, stream>>>(x, aw, ab, attn);
    k2_stats<<<dim3(8192),  dim3(256), 0, stream>>>(x, attn, bn_sum, bn_sumsq);
    k3_final<<<dim3(1),     dim3(256), 0, stream>>>(bn_sum, bn_sumsq, gamma, beta, scale, shift);
    k4_gate <<<dim3(896),   dim3(256), 0, stream>>>(x, attn, scale, shift, gw0, gw1, gate_raw);
    k4b_tanh<<<dim3(1568),  dim3(256), 0, stream>>>(gate_raw, gb0, gb1, gate_t);
    k5_fuse <<<dim3(13312), dim3(256), 0, stream>>>(x, attn, scale, shift, gate_t, alpha, out);
}

// Round 2
// 308.964 us; speedup vs baseline: 1.5743x; 1.5743x over previous
//
#include <hip/hip_runtime.h>
#include <math.h>

#define HH 56
#define WW 56
#define CC 256
#define TT 8
#define HW 3136

// ---------------- K1: attn partial conv2d, channel-split + atomics --------
// grid = bt(32) x hwtile(13) x csplit(4); thread = one output pixel.
// Weights for this 64-channel split staged in LDS as float4 [cl][tap][4 heads];
// all reads wave-uniform -> broadcast, no bank conflicts. x read direct from
// global (L1-resident planes), 9 predicated taps with hoisted bounds masks.
__global__ __launch_bounds__(256)
void k1_attn(const float* __restrict__ x, const float* __restrict__ aw,
             float* __restrict__ attn_raw) {
    const int blk  = blockIdx.x;
    const int cs   = blk & 3;
    const int tile = (blk >> 2) % 13;
    const int bt   = blk / 52;
    const int hw   = tile * 256 + threadIdx.x;

    __shared__ float wl[64][9][4];          // 9216 B
    for (int i = threadIdx.x; i < 64 * 9 * 4; i += 256) {
        int cl  = i / 36;
        int rem = i - cl * 36;
        int tap = rem >> 2;
        int o   = rem & 3;
        wl[cl][tap][o] = aw[((size_t)o * CC + cs * 64 + cl) * 9 + tap];
    }
    __syncthreads();

    const bool valid = hw < HW;
    const int row = hw / WW, col = hw % WW;
    int  off[9];
    bool ok[9];
    #pragma unroll
    for (int ki = 0; ki < 3; ++ki)
        #pragma unroll
        for (int kj = 0; kj < 3; ++kj) {
            int r = row + ki - 1, cc = col + kj - 1;
            ok[ki * 3 + kj]  = valid && (unsigned)r < HH && (unsigned)cc < WW;
            off[ki * 3 + kj] = r * WW + cc;
        }

    float acc0 = 0.f, acc1 = 0.f, acc2 = 0.f, acc3 = 0.f;
    const float* xb = x + ((size_t)bt * CC + cs * 64) * HW;
    #pragma unroll 2
    for (int cl = 0; cl < 64; ++cl) {
        const float* xp = xb + (size_t)cl * HW;
        #pragma unroll
        for (int tap = 0; tap < 9; ++tap) {
            float v = ok[tap] ? xp[off[tap]] : 0.f;
            const float4 w = *(const float4*)&wl[cl][tap][0];
            acc0 = fmaf(w.x, v, acc0);
            acc1 = fmaf(w.y, v, acc1);
            acc2 = fmaf(w.z, v, acc2);
            acc3 = fmaf(w.w, v, acc3);
        }
    }
    if (valid) {
        atomicAdd(&attn_raw[((size_t)bt * 4 + 0) * HW + hw], acc0);
        atomicAdd(&attn_raw[((size_t)bt * 4 + 1) * HW + hw], acc1);
        atomicAdd(&attn_raw[((size_t)bt * 4 + 2) * HW + hw], acc2);
        atomicAdd(&attn_raw[((size_t)bt * 4 + 3) * HW + hw], acc3);
    }
}

// ---------------- K1b: attn = sigmoid(relu(raw + bias)) -------------------
__global__ void k1b_act(const float* __restrict__ raw, const float* __restrict__ ab,
                        float* __restrict__ attn) {
    int i = blockIdx.x * 256 + threadIdx.x;
    if (i >= 32 * 4 * HW) return;
    int o = (i / HW) & 3;
    float z = fmaxf(raw[i] + ab[o], 0.f);
    attn[i] = 1.f / (1.f + expf(-z));
}

// ---------------- K2: per-channel BN partial sums of xh = x*attn ----------
__global__ __launch_bounds__(256)
void k2_stats(const float* __restrict__ x, const float* __restrict__ attn,
              float* __restrict__ bn_sum, float* __restrict__ bn_sumsq) {
    const int c  = blockIdx.x & 255;
    const int bt = blockIdx.x >> 8;
    const int head = c >> 6;
    const float4* xp = (const float4*)(x + ((size_t)bt * CC + c) * HW);
    const float4* ap = (const float4*)(attn + ((size_t)bt * 4 + head) * HW);
    float s = 0.f, s2 = 0.f;
    for (int i = threadIdx.x; i < HW / 4; i += 256) {
        float4 xv = xp[i], av = ap[i];
        float v0 = xv.x * av.x, v1 = xv.y * av.y, v2 = xv.z * av.z, v3 = xv.w * av.w;
        s  += v0 + v1 + v2 + v3;
        s2 += v0 * v0 + v1 * v1 + v2 * v2 + v3 * v3;
    }
    #pragma unroll
    for (int off = 32; off > 0; off >>= 1) {
        s  += __shfl_down(s, off);
        s2 += __shfl_down(s2, off);
    }
    __shared__ float red[8];
    const int wave = threadIdx.x >> 6;
    if ((threadIdx.x & 63) == 0) { red[wave * 2] = s; red[wave * 2 + 1] = s2; }
    __syncthreads();
    if (threadIdx.x == 0) {
        atomicAdd(&bn_sum[c],   red[0] + red[2] + red[4] + red[6]);
        atomicAdd(&bn_sumsq[c], red[1] + red[3] + red[5] + red[7]);
    }
}

// ---------------- K3: finalize BN -> per-channel scale/shift --------------
__global__ void k3_final(const float* __restrict__ bn_sum, const float* __restrict__ bn_sumsq,
                         const float* __restrict__ gamma, const float* __restrict__ beta,
                         float* __restrict__ scale, float* __restrict__ shift) {
    int c = threadIdx.x;
    const float invN = 1.f / 100352.f;            // B*T*H*W
    float mean = bn_sum[c] * invN;
    float var  = bn_sumsq[c] * invN - mean * mean;
    float sc   = gamma[c] * rsqrtf(var + 1e-5f);
    scale[c] = sc;
    shift[c] = fmaf(-mean, sc, beta[c]);
}

// ---------------- K4: grouped dilated conv3d partial sums -----------------
// block = (b, 4-row h-tile, 8-channel chunk): 1792 blocks for occupancy.
__global__ __launch_bounds__(256)
void k4_gate(const float* __restrict__ x, const float* __restrict__ attn,
             const float* __restrict__ scale, const float* __restrict__ shift,
             const float* __restrict__ gw0, const float* __restrict__ gw1,
             float* __restrict__ gate_raw) {
    const int blk   = blockIdx.x;
    const int chunk = blk & 31;             // 32 chunks x 8 channels
    const int ht    = (blk >> 5) % 14;
    const int b     = blk / (32 * 14);
    const int h0    = ht * 4;
    const int g     = chunk >> 4;           // channels 0..127 -> g0, 128..255 -> g1
    __shared__ float tile[TT][6][58];       // 11136 B
    const int tid = threadIdx.x;
    const int wc  = tid % WW;
    const int hr  = tid / WW;
    const bool active = tid < 4 * WW;
    float acc[2][8];
    #pragma unroll
    for (int d = 0; d < 2; ++d)
        #pragma unroll
        for (int t = 0; t < 8; ++t) acc[d][t] = 0.f;

    for (int cl = 0; cl < 8; ++cl) {
        const int c = chunk * 8 + cl;
        const float sc = scale[c], sh = shift[c];
        const int head = c >> 6;
        __syncthreads();
        // stage xr = relu(x*attn*sc + sh) for all 8 t planes, with spatial halo
        for (int idx = tid; idx < TT * 6 * 58; idx += 256) {
            int t   = idx / 348;
            int rem = idx - t * 348;
            int r   = rem / 58;
            int col = rem - r * 58;
            int gh = h0 + r - 1, gw = col - 1;
            float v = 0.f;
            if (gh >= 0 && gh < HH && (unsigned)gw < WW) {
                int bti = b * TT + t;
                float xv = x[((size_t)bti * CC + c) * HW + gh * WW + gw];
                float av = attn[((size_t)bti * 4 + head) * HW + gh * WW + gw];
                v = fmaxf(fmaf(xv * av, sc, sh), 0.f);
            }
            tile[t][r][col] = v;
        }
        __syncthreads();
        if (active) {
            const int ci = c & 127;
            const float* wp0 = gw0 + ((size_t)g * 128 + ci) * 27;  // dil 1 weights
            const float* wp1 = gw1 + ((size_t)g * 128 + ci) * 27;  // dil 2 weights
            #pragma unroll
            for (int t = 0; t < 8; ++t) {     // t_in
                float v[9];
                #pragma unroll
                for (int ki = 0; ki < 3; ++ki)
                    #pragma unroll
                    for (int kj = 0; kj < 3; ++kj)
                        v[ki * 3 + kj] = tile[t][hr + ki][wc + kj];
                #pragma unroll
                for (int kd = 0; kd < 3; ++kd) {
                    {   // dilation 1: t_out = t_in + (1-kd)*1
                        const int to = t + (1 - kd);
                        if (to >= 0 && to < 8) {
                            float s = 0.f;
                            #pragma unroll
                            for (int k = 0; k < 9; ++k) s = fmaf(wp0[kd * 9 + k], v[k], s);
                            acc[0][to] += s;
                        }
                    }
                    {   // dilation 2: t_out = t_in + (1-kd)*2
                        const int to = t + 2 * (1 - kd);
                        if (to >= 0 && to < 8) {
                            float s = 0.f;
                            #pragma unroll
                            for (int k = 0; k < 9; ++k) s = fmaf(wp1[kd * 9 + k], v[k], s);
                            acc[1][to] += s;
                        }
                    }
                }
            }
        }
    }
    if (active) {
        #pragma unroll
        for (int d = 0; d < 2; ++d)
            #pragma unroll
            for (int t = 0; t < 8; ++t)
                atomicAdd(&gate_raw[(((size_t)(d * 4 + b) * 2 + g) * 8 + t) * HW
                                    + (h0 + hr) * WW + wc], acc[d][t]);
    }
}

// ---------------- K4b: gate = tanh(raw + bias) ----------------------------
__global__ void k4b_tanh(const float* __restrict__ raw, const float* __restrict__ gb0,
                         const float* __restrict__ gb1, float* __restrict__ gt) {
    int i = blockIdx.x * 256 + threadIdx.x;
    if (i >= 401408) return;
    int d   = i / 200704;
    int rem = i - d * 200704;
    int g   = (rem / 25088) & 1;        // 8*3136 per (g) slab
    float bias = (d == 0) ? gb0[g] : gb1[g];
    gt[i] = tanhf(raw[i] + bias);
}

// ---------------- K5: fuse + shuffle + alpha-combine ----------------------
// thread owns (b, c_out, hw) across all 8 t: x read exactly once.
__global__ __launch_bounds__(256)
void k5_fuse(const float* __restrict__ x, const float* __restrict__ attn,
             const float* __restrict__ scale, const float* __restrict__ shift,
             const float* __restrict__ gt, const float* __restrict__ alpha,
             float* __restrict__ out) {
    const int blk  = blockIdx.x;
    const int tile = blk % 13;
    const int c    = (blk / 13) & 255;
    const int b    = blk / (13 * 256);
    const int hw   = tile * 256 + threadIdx.x;
    if (hw >= HW) return;
    const int clo  = c & 127;
    const int cs   = (c & 128) | ((clo & 1) << 6) | (clo >> 1);  // inverse shuffle
    const int g    = c >> 7;
    const int head = cs >> 6;
    const float sc = scale[cs], sh = shift[cs];
    float xr[8], G0[8], G1[8];
    #pragma unroll
    for (int t = 0; t < 8; ++t) {
        const int bti = b * 8 + t;
        float xv = x[((size_t)bti * CC + cs) * HW + hw];
        float av = attn[((size_t)bti * 4 + head) * HW + hw];
        xr[t] = fmaxf(fmaf(xv * av, sc, sh), 0.f);
        G0[t] = gt[(((size_t)(0 * 4 + b) * 2 + g) * 8 + t) * HW + hw];
        G1[t] = gt[(((size_t)(1 * 4 + b) * 2 + g) * 8 + t) * HW + hw];
    }
    const float a0 = alpha[0], a1 = alpha[1];
    #pragma unroll
    for (int t = 0; t < 8; ++t) {
        float v0, v1;
        if (g == 0) {   // shift-left group: neighbor at t+d
            v0 = xr[t] * (1.f - G0[t]) + (t + 1 < 8 ? G0[t + 1] * xr[t + 1] : 0.f);
            v1 = xr[t] * (1.f - G1[t]) + (t + 2 < 8 ? G1[t + 2] * xr[t + 2] : 0.f);
        } else {        // shift-right group: neighbor at t-d
            v0 = xr[t] * (1.f - G0[t]) + (t - 1 >= 0 ? G0[t - 1] * xr[t - 1] : 0.f);
            v1 = xr[t] * (1.f - G1[t]) + (t - 2 >= 0 ? G1[t - 2] * xr[t - 2] : 0.f);
        }
        out[((size_t)(b * 8 + t) * CC + c) * HW + hw] = fmaf(a0, v0, a1 * v1);
    }
}

extern "C" void kernel_launch(void* const* d_in, const int* in_sizes, int n_in,
                              void* d_out, int out_size, void* d_ws, size_t ws_size,
                              hipStream_t stream) {
    const float* x     = (const float*)d_in[0];
    const float* aw    = (const float*)d_in[1];
    const float* ab    = (const float*)d_in[2];
    const float* gamma = (const float*)d_in[3];
    const float* beta  = (const float*)d_in[4];
    const float* gw0   = (const float*)d_in[5];
    const float* gb0   = (const float*)d_in[6];
    const float* gw1   = (const float*)d_in[7];
    const float* gb1   = (const float*)d_in[8];
    const float* alpha = (const float*)d_in[9];
    float* out = (float*)d_out;
    float* ws  = (float*)d_ws;

    // ws layout (floats):
    //   [gate_raw 401408 | attn_raw/gate_t 401408 | bn_sum 256 | bn_sumsq 256 |
    //    attn 401408 | scale 256 | shift 256]
    // attn_raw is dead after k1b; k4b fully overwrites the slot as gate_t.
    float* gate_raw = ws;
    float* attn_raw = ws + 401408;
    float* gate_t   = attn_raw;             // alias (timeline-disjoint)
    float* bn_sum   = ws + 802816;
    float* bn_sumsq = ws + 803072;
    float* attn     = ws + 803328;
    float* scale    = ws + 1204736;
    float* shift    = ws + 1204992;

    // zero all atomic-accumulated regions in one memset (contiguous prefix)
    hipMemsetAsync(ws, 0, (size_t)(401408 + 401408 + 512) * sizeof(float), stream);

    k1_attn <<<dim3(1664),  dim3(256), 0, stream>>>(x, aw, attn_raw);
    k1b_act <<<dim3(1568),  dim3(256), 0, stream>>>(attn_raw, ab, attn);
    k2_stats<<<dim3(8192),  dim3(256), 0, stream>>>(x, attn, bn_sum, bn_sumsq);
    k3_final<<<dim3(1),     dim3(256), 0, stream>>>(bn_sum, bn_sumsq, gamma, beta, scale, shift);
    k4_gate <<<dim3(1792),  dim3(256), 0, stream>>>(x, attn, scale, shift, gw0, gw1, gate_raw);
    k4b_tanh<<<dim3(1568),  dim3(256), 0, stream>>>(gate_raw, gb0, gb1, gate_t);
    k5_fuse <<<dim3(13312), dim3(256), 0, stream>>>(x, attn, scale, shift, gate_t, alpha, out);
}